// Round 8
// baseline (254.017 us; speedup 1.0000x reference)
//
#include <hip/hip_runtime.h>
#include <cstdint>
#include <cstddef>

// Problem constants (VectorQuantizer: L=32768, D=64, N_E=16384, beta=0.25)
#define L_TOK 32768
#define D_DIM 64
#define NE    16384
#define GCHUNKS 4              // N split across grid
#define NPB   (NE / GCHUNKS)   // 4096 n per block
#define BN    128              // n per LDS stage chunk
#define WROWS 32               // rows per wave (2 MFMA row-groups)
#define BROWS 128              // rows per block (4 waves x 32)
#define AMBLOCKS (GCHUNKS * (L_TOK / BROWS))   // 1024 argmin blocks
#define RBLOCKS  (L_TOK / 32)                  // 1024 refine blocks

#define ASCALE  -4194304.0f    // -2^22: A-fragment pre-scale (exact pow2)
#define ESCALE   2097152.0f    // 2^21 = 0.5*2^22 for esq
#define KBIAS_F  32768.0f      // 2^15 bias, folded into esqs at prep

typedef unsigned short ushort_t;
typedef __attribute__((ext_vector_type(8))) short bf16x8;
typedef __attribute__((ext_vector_type(4))) float f32x4;

// ---- ws layout (bytes) ----
#define WS_EHI   0u                                  // 2 MB   e bf16(RNE) permuted
#define WS_ESQ32 (2u<<20)                            // 64 KB  esq np-exact fp32
#define WS_ESQS  ((2u<<20) + (64u<<10))              // 64 KB  esq*2^21 + 2^15
#define WS_ESQ64 ((2u<<20) + (128u<<10))             // 128 KB esq fp64 (loss)
#define WS_CAND  ((2u<<20) + (256u<<10))             // 2 MB   cand[4][L][4] int
#define WS_ACC   ((4u<<20) + (256u<<10))             // 8 B    loss accumulator (dbl)
#define WS_CNT   ((4u<<20) + (256u<<10) + 8u)        // 4 B    done counter (int)

__device__ __forceinline__ ushort_t bf16_rne(float v) {
  unsigned u = __float_as_uint(v);
  return (ushort_t)((u + 0x7fffu + ((u >> 16) & 1u)) >> 16);
}

// v_med3_u32: median(a,b,c). With b<=c this equals min(max(a,b),c) — the
// top-k insertion step. The compiler can't prove the invariant, so ask for
// the instruction directly.
__device__ __forceinline__ unsigned umed3(unsigned a, unsigned b, unsigned c) {
  unsigned d;
  asm("v_med3_u32 %0, %1, %2, %3" : "=v"(d) : "v"(a), "v"(b), "v"(c));
  return d;
}

// numpy pairwise_sum emulation for n=64 contiguous fp32 (scalar 8-acc path).
__device__ __forceinline__ float np_sum64(float a) {
  int j = threadIdx.x & 7;
  float r = __shfl(a, j);
  #pragma unroll
  for (int m = 1; m < 8; ++m) r += __shfl(a, j + 8 * m);
  float s0 = __shfl(r, 0), s1 = __shfl(r, 1), s2 = __shfl(r, 2), s3 = __shfl(r, 3);
  float s4 = __shfl(r, 4), s5 = __shfl(r, 5), s6 = __shfl(r, 6), s7 = __shfl(r, 7);
  return ((s0 + s1) + (s2 + s3)) + ((s4 + s5) + (s6 + s7));
}

// Fragment-permuted index (in ushorts) for element (n, k) — LDS staging order
// equals MFMA B-fragment consumption order (conflict-free ds_read_b128).
__device__ __forceinline__ int perm_off(int n, int k) {
  int tile = n >> 4, c = n & 15, s = k >> 5, q = (k >> 3) & 3, j = k & 7;
  return tile * 1024 + s * 512 + (q * 16 + c) * 8 + j;
}

// ---------------- kernel 1: prep embedding -----------------------------------
__global__ __launch_bounds__(256) void vq_prep_e(const float* __restrict__ e,
                                                 ushort_t* __restrict__ ehi,
                                                 float* __restrict__ esq32,
                                                 float* __restrict__ esqs,
                                                 double* __restrict__ esq64,
                                                 double* __restrict__ loss_acc,
                                                 int* __restrict__ done_cnt) {
  if (blockIdx.x == 0 && threadIdx.x == 0) { *loss_acc = 0.0; *done_cnt = 0; }
  int wave = threadIdx.x >> 6, lane = threadIdx.x & 63;
  int row = blockIdx.x * 4 + wave;            // one wave per embedding row
  float v = e[(size_t)row * D_DIM + lane];
  ehi[perm_off(row, lane)] = bf16_rne(v);
  float esq = np_sum64(v * v);                // numpy-bit-exact sum(e*e, axis=1)
  double p = (double)v * (double)v;
  #pragma unroll
  for (int o = 32; o; o >>= 1) p += __shfl_xor(p, o);
  if (lane == 0) {
    esq32[row] = esq;                         // exact rescore
    esqs[row]  = esq * ESCALE + KBIAS_F;      // sieve MFMA C operand
    esq64[row] = p;                           // loss
  }
}

// ---------------- kernel 2: fused distance + per-row top-k sieve -------------
// grid = dim3(GCHUNKS, L/BROWS) = 1024 blocks, block = 256 (4 waves x 32 rows)
// LDS 24 KB -> 6 blocks/CU (24 waves/CU) for issue-pipe saturation.
// A is pre-scaled by -2^22 and esq*2^21+2^15 rides in as the MFMA C operand,
// so the accumulator directly equals the sieve key 2^22*d + 2^15 (positive by
// Cauchy-Schwarz: |dot|*2^22 < 24k < 2^15).  Packed key:
// (trunc(acc) << 12) | (tile*16 + c)  — 16-bit magnitude (2.4e-7 buckets in d,
// << the ~1e-5 np-fp32 window the refine resolves), ties break toward lower n.
__global__ __launch_bounds__(256, 6) void vq_argmin(const float* __restrict__ z,
                                                    const ushort_t* __restrict__ ehi,
                                                    const float* __restrict__ esqs,
                                                    int* __restrict__ cand) {
  __shared__ __align__(16) unsigned char smem[24576]; // staging 16.5KB / merge 24KB
  ushort_t* s_ehi = (ushort_t*)smem;
  float*    s_esq = (float*)(smem + 16384);

  const int tid = threadIdx.x;
  const int wave = tid >> 6, lane = tid & 63;
  const int q = lane >> 4, c = lane & 15;
  const int row0 = blockIdx.y * BROWS + wave * WROWS;
  const int nbase = blockIdx.x * NPB;

  // A fragments: two row-groups of 16, bf16(RNE) of -2^22*z in-register.
  // A layout: lane holds A[m=lane&15][k = q*8 + j (+32 for k-step 1)]
  bf16x8 zA[2][2];
  #pragma unroll
  for (int g = 0; g < 2; ++g) {
    const float* zr = z + (size_t)(row0 + g * 16 + c) * D_DIM;
    float4 a0 = *(const float4*)(zr + q * 8);
    float4 a1 = *(const float4*)(zr + q * 8 + 4);
    float4 a2 = *(const float4*)(zr + 32 + q * 8);
    float4 a3 = *(const float4*)(zr + 32 + q * 8 + 4);
    zA[g][0][0] = (short)bf16_rne(a0.x * ASCALE); zA[g][0][1] = (short)bf16_rne(a0.y * ASCALE);
    zA[g][0][2] = (short)bf16_rne(a0.z * ASCALE); zA[g][0][3] = (short)bf16_rne(a0.w * ASCALE);
    zA[g][0][4] = (short)bf16_rne(a1.x * ASCALE); zA[g][0][5] = (short)bf16_rne(a1.y * ASCALE);
    zA[g][0][6] = (short)bf16_rne(a1.z * ASCALE); zA[g][0][7] = (short)bf16_rne(a1.w * ASCALE);
    zA[g][1][0] = (short)bf16_rne(a2.x * ASCALE); zA[g][1][1] = (short)bf16_rne(a2.y * ASCALE);
    zA[g][1][2] = (short)bf16_rne(a2.z * ASCALE); zA[g][1][3] = (short)bf16_rne(a2.w * ASCALE);
    zA[g][1][4] = (short)bf16_rne(a3.x * ASCALE); zA[g][1][5] = (short)bf16_rne(a3.y * ASCALE);
    zA[g][1][6] = (short)bf16_rne(a3.z * ASCALE); zA[g][1][7] = (short)bf16_rne(a3.w * ASCALE);
  }

  // per-(rowgroup g, acc row r) top-3 packed-key tracking (24 VGPRs),
  // invariant K0 <= K1 <= K2 (init equal, preserved by med3 insertion)
  unsigned K0[2][4], K1[2][4], K2[2][4];
  #pragma unroll
  for (int g = 0; g < 2; ++g)
    #pragma unroll
    for (int r = 0; r < 4; ++r) {
      K0[g][r] = 0xFFFFFFFFu; K1[g][r] = 0xFFFFFFFFu; K2[g][r] = 0xFFFFFFFFu;
    }

  for (int cb = 0; cb < NPB / BN; ++cb) {
    int nch = nbase + cb * BN;
    __syncthreads();   // previous chunk's LDS reads done
    {
      const uint4* gh = ((const uint4*)ehi) + (size_t)nch * 8;  // 8 uint4 per n
      uint4* sb = (uint4*)s_ehi;                                // 1024 uint4
      uint4 v0 = gh[tid], v1 = gh[tid + 256], v2 = gh[tid + 512], v3 = gh[tid + 768];
      sb[tid] = v0; sb[tid + 256] = v1; sb[tid + 512] = v2; sb[tid + 768] = v3;
      if (tid < BN) s_esq[tid] = esqs[nch + tid];
    }
    __syncthreads();

    #pragma unroll 4
    for (int t = 0; t < BN / 16; ++t) {
      const bf16x8 bh0 = *(const bf16x8*)(s_ehi + t * 1024 + lane * 8);
      const bf16x8 bh1 = *(const bf16x8*)(s_ehi + t * 1024 + 512 + lane * 8);
      float esqv = s_esq[t * 16 + c];
      f32x4 cvec = {esqv, esqv, esqv, esqv};       // key bias rides in as C
      unsigned tcv = (((unsigned)(cb * 8 + t)) << 4) | (unsigned)c;  // n_local
      f32x4 acc0 = __builtin_amdgcn_mfma_f32_16x16x32_bf16(zA[0][0], bh0, cvec, 0, 0, 0);
      acc0 = __builtin_amdgcn_mfma_f32_16x16x32_bf16(zA[0][1], bh1, acc0, 0, 0, 0);
      f32x4 acc1 = __builtin_amdgcn_mfma_f32_16x16x32_bf16(zA[1][0], bh0, cvec, 0, 0, 0);
      acc1 = __builtin_amdgcn_mfma_f32_16x16x32_bf16(zA[1][1], bh1, acc1, 0, 0, 0);
      #pragma unroll
      for (int r = 0; r < 4; ++r) {
        unsigned pk = (((unsigned)acc0[r]) << 12) | tcv;   // cvt + lshl_or
        K2[0][r] = umed3(pk, K1[0][r], K2[0][r]);
        K1[0][r] = umed3(pk, K0[0][r], K1[0][r]);
        K0[0][r] = min(pk, K0[0][r]);
      }
      #pragma unroll
      for (int r = 0; r < 4; ++r) {
        unsigned pk = (((unsigned)acc1[r]) << 12) | tcv;
        K2[1][r] = umed3(pk, K1[1][r], K2[1][r]);
        K1[1][r] = umed3(pk, K0[1][r], K1[1][r]);
        K0[1][r] = min(pk, K0[1][r]);
      }
    }
  }

  // merge 16 lanes' top-3 -> per-row top-4 for this chunk
  __syncthreads();
  unsigned* s_k = (unsigned*)smem;             // [128 rows][16 c][3] = 24 KB
  #pragma unroll
  for (int g = 0; g < 2; ++g)
    #pragma unroll
    for (int r = 0; r < 4; ++r) {
      int rowidx = wave * WROWS + g * 16 + q * 4 + r;  // C layout: row = q*4 + reg
      int base = (rowidx * 16 + c) * 3;
      s_k[base + 0] = K0[g][r]; s_k[base + 1] = K1[g][r]; s_k[base + 2] = K2[g][r];
    }
  __syncthreads();
  if (tid < BROWS) {
    unsigned M0 = 0xFFFFFFFFu, M1 = 0xFFFFFFFFu, M2 = 0xFFFFFFFFu, M3 = 0xFFFFFFFFu;
    const uint4* sv = (const uint4*)(s_k + tid * 48);
    #pragma unroll
    for (int v4 = 0; v4 < 12; ++v4) {
      uint4 kk = sv[v4];
      unsigned vals[4] = {kk.x, kk.y, kk.z, kk.w};
      #pragma unroll
      for (int u = 0; u < 4; ++u) {
        unsigned v = vals[u];
        M3 = umed3(v, M2, M3);
        M2 = umed3(v, M1, M2);
        M1 = umed3(v, M0, M1);
        M0 = min(v, M0);
      }
    }
    int grow = blockIdx.y * BROWS + tid;
    int* cp = cand + ((size_t)blockIdx.x * L_TOK + grow) * 4;
    cp[0] = (int)(nbase + (M0 & 4095u)); cp[1] = (int)(nbase + (M1 & 4095u));
    cp[2] = (int)(nbase + (M2 & 4095u)); cp[3] = (int)(nbase + (M3 & 4095u));
  }
}

// ------- kernel 3: np-fp32-exact rescore of 16 candidates, outputs ----------
// grid = L/32 blocks, block 512 (8 waves); each wave: 4 rows, 4 lanes/candidate.
// zsq (np-exact fp32 + fp64) computed inline; loss finalized by last block.
__global__ __launch_bounds__(512, 4) void vq_refine(const float* __restrict__ z,
                                                    const float* __restrict__ e,
                                                    const float* __restrict__ esq32,
                                                    const double* __restrict__ esq64,
                                                    const int* __restrict__ cand,
                                                    float* __restrict__ out,
                                                    double* __restrict__ loss_acc,
                                                    int* __restrict__ done_cnt) {
  const int tid = threadIdx.x;
  const int wave = tid >> 6, lane = tid & 63;
  const int g = lane >> 2, s = lane & 3;      // 16 cand-groups x 4 lanes
  __shared__ double sp[8];
  double wl = 0.0;
  for (int it = 0; it < 4; ++it) {
    int row = blockIdx.x * 32 + wave * 4 + it;
    float zf = z[(size_t)row * D_DIM + lane];
    float zsqv = np_sum64(zf * zf);            // numpy-bit-exact sum(z*z, axis=1)
    double zp64 = (double)zf * (double)zf;
    #pragma unroll
    for (int o = 32; o; o >>= 1) zp64 += __shfl_xor(zp64, o);
    int idx = cand[((size_t)(g >> 2) * L_TOK + row) * 4 + (g & 3)];
    // fp64 dot over 16 elements/lane, then 2-step in-group reduce
    const float4* ep = (const float4*)(e + (size_t)idx * D_DIM + s * 16);
    const float4* zp = (const float4*)(z + (size_t)row * D_DIM + s * 16);
    double dot = 0.0;
    #pragma unroll
    for (int j = 0; j < 4; ++j) {
      float4 ev = ep[j], zv = zp[j];
      dot = fma((double)ev.x, (double)zv.x, dot);
      dot = fma((double)ev.y, (double)zv.y, dot);
      dot = fma((double)ev.z, (double)zv.z, dot);
      dot = fma((double)ev.w, (double)zv.w, dot);
    }
    dot += __shfl_xor(dot, 1);
    dot += __shfl_xor(dot, 2);
    // emulate np fp32: d = fl32( fl32(zsq + esq) - fl32(2*dot) )
    float t2 = (float)(2.0 * dot);
    float T1 = zsqv + esq32[idx];
    float d  = T1 - t2;                        // d ~ 64 > 0: bits are monotone
    unsigned long long key = ((unsigned long long)__float_as_uint(d) << 14)
                           | (unsigned)idx;    // tie -> lower idx (np.argmin)
    double dotw = dot;
    #pragma unroll
    for (int o = 4; o <= 32; o <<= 1) {
      unsigned long long ok = __shfl_xor(key, o);
      double od = __shfl_xor(dotw, o);
      bool take = ok < key;
      key  = take ? ok : key;
      dotw = take ? od : dotw;
    }
    int win = (int)(key & 16383u);
    // outputs (element layout; whole wave)
    float be = e[(size_t)win * D_DIM + lane];
    out[(size_t)row * D_DIM + lane] = zf + (be - zf);   // fp32 op-order ST
    if (lane == 0) {
      out[(size_t)L_TOK * D_DIM + 1 + row] = (float)win;
      wl += zp64 + esq64[win] - 2.0 * dotw;             // ||z - e_win||^2 (fp64)
    }
  }
  if (lane == 0) sp[wave] = wl;
  __syncthreads();
  if (tid == 0) {
    double t = 0.0;
    #pragma unroll
    for (int w = 0; w < 8; ++w) t += sp[w];
    double prev = atomicAdd(loss_acc, t);       // device-scope
    __threadfence();
    int done = atomicAdd(done_cnt, 1);
    if (done == RBLOCKS - 1) {
      double tot = prev + t;                    // this add completed the sum
      // all other adds happened-before their counter-incs (fence), and we saw
      // all incs — but `prev` already includes them since our RMW was atomic
      // and performed after... re-read authoritative value instead:
      tot = atomicAdd(loss_acc, 0.0);           // returns final sum
      // loss = beta*mean + mean = 1.25 * mean((z_q - z)^2)
      out[(size_t)L_TOK * D_DIM] = (float)(1.25 * tot / (double)((size_t)L_TOK * D_DIM));
    }
  }
}

extern "C" void kernel_launch(void* const* d_in, const int* in_sizes, int n_in,
                              void* d_out, int out_size, void* d_ws, size_t ws_size,
                              hipStream_t stream) {
  const float* z = (const float*)d_in[0];       // (32768, 64) fp32
  const float* e = (const float*)d_in[1];       // (16384, 64) fp32
  float* out = (float*)d_out;                   // [z_q_st | loss | indices-as-f32]
  char* ws = (char*)d_ws;                       // needs ~4.3 MB

  ushort_t* ehi   = (ushort_t*)(ws + WS_EHI);
  float*    esq32 = (float*)(ws + WS_ESQ32);
  float*    esqs  = (float*)(ws + WS_ESQS);
  double*   esq64 = (double*)(ws + WS_ESQ64);
  int*      cand  = (int*)(ws + WS_CAND);
  double*   lacc  = (double*)(ws + WS_ACC);
  int*      dcnt  = (int*)(ws + WS_CNT);

  vq_prep_e<<<NE / 4, 256, 0, stream>>>(e, ehi, esq32, esqs, esq64, lacc, dcnt);
  vq_argmin<<<dim3(GCHUNKS, L_TOK / BROWS), 256, 0, stream>>>(z, ehi, esqs, cand);
  vq_refine<<<RBLOCKS, 512, 0, stream>>>(z, e, esq32, esq64, cand, out, lacc, dcnt);
}